// Round 12
// baseline (198.798 us; speedup 1.0000x reference)
//
#include <hip/hip_runtime.h>
#include <hip/hip_bf16.h>

#define TPB 512  // 8 waves
#define BM 32
#define NROW 32768
#define NBLK (NROW / BM)  // 1024
#define VV 1024
#define KD 256
#define TT 2048

#define LP_OFF 2L
#define ZQ_OFF (2L + 33554432L)
#define EM_OFF (33554434L + 8388608L)

// ws layout (floats)
#define WS_HIST 0
#define WS_CSUM 1024
#define WS_SSUM 2048
#define WS_MSUM 3072
#define WS_E8 4096  // bf16 e, 512 KB: [s8][w8][g4][nt8][lm16] 16B units
#define WS_NEED ((size_t)(4096 + 131072) * 4)

typedef __attribute__((ext_vector_type(8))) short bf16x8;
typedef __attribute__((ext_vector_type(4))) float f32x4;

__device__ __forceinline__ void gl_lds16(const void* g, void* l) {
  __builtin_amdgcn_global_load_lds(
      (const __attribute__((address_space(1))) void*)g,
      (__attribute__((address_space(3))) void*)l, 16, 0, 0);
}

__device__ __forceinline__ unsigned short f2bf(float x) {  // RNE
  unsigned u = __float_as_uint(x);
  unsigned r = ((u >> 16) & 1u) + 0x7FFFu;
  return (unsigned short)((u + r) >> 16);
}

__device__ __forceinline__ unsigned foldf(float v) {  // order-preserving
  unsigned b = __float_as_uint(v);
  return b ^ ((unsigned)((int)b >> 31) | 0x80000000u);
}
__device__ __forceinline__ float unfoldf(unsigned k) {
  unsigned s = (unsigned)((int)k >> 31);
  return __uint_as_float(k ^ (0x80000000u | (~s & 0x7FFFFFFFu)));
}

__device__ __forceinline__ int4 pack8(const float* p) {
  float4 a = *(const float4*)p;
  float4 b = *(const float4*)(p + 4);
  int4 pk;
  pk.x = f2bf(a.x) | ((unsigned)f2bf(a.y) << 16);
  pk.y = f2bf(a.z) | ((unsigned)f2bf(a.w) << 16);
  pk.z = f2bf(b.x) | ((unsigned)f2bf(b.y) << 16);
  pk.w = f2bf(b.z) | ((unsigned)f2bf(b.w) << 16);
  return pk;
}

// e8 unit t: s=t>>12, w=(t>>9)&7, g=(t>>7)&3, c=t&127 -> col n=w*128+c,
// oct o=s*4+g. Per-(s,w) slice = 8 KB contiguous.
__global__ __launch_bounds__(256) void tok_prep(const float* __restrict__ cw,
                                                unsigned short* __restrict__ e8) {
  int t = blockIdx.x * 256 + threadIdx.x;  // 32768
  int s = t >> 12, w = (t >> 9) & 7, g = (t >> 7) & 3, c = t & 127;
  int n = (w << 7) + c;
  int o = (s << 2) + g;
  *(int4*)(e8 + ((size_t)t << 3)) = pack8(cw + (size_t)(1 + n) * KD + (o << 3));
}

__global__ __launch_bounds__(TPB, 4) void tok_mfma(
    const float* __restrict__ z, const float* __restrict__ mask,
    const float* __restrict__ cw, const unsigned short* __restrict__ e8,
    float* __restrict__ out, float* __restrict__ ws) {
  // z8 bf16 A-planes (K-loop) ... then overlaid epilogue pool (post-barrier)
  __shared__ __align__(16) unsigned char smem[16384];
  unsigned(*wkey)[2][33] = (unsigned(*)[2][33])smem;          // 2112
  float(*wsum)[33] = (float(*)[33])(smem + 2112);             // 1056
  float* lse_s = (float*)(smem + 3168);                       // 128
  float(*exv_s)[4] = (float(*)[4])(smem + 3296);              // 512
  int(*exi_s)[4] = (int(*)[4])(smem + 3808);                  // 512
  int* argi = (int*)(smem + 4320);                            // 128
  float* cred = (float*)(smem + 4448);                        // 32
  float* sred = (float*)(smem + 4480);                        // 32

  const int tid = threadIdx.x;
  const int lane = tid & 63;
  const int w = tid >> 6;   // 0..7
  const int g = lane >> 4;  // 0..3
  const int lm = lane & 15;
  const int c0 = w << 7;  // wave's 128-col base
  const int n0 = blockIdx.x * BM;

  // ---- prologue: z rows -> regs -> bf16 -> swizzled z8 LDS ----
  {
    const int zr = (w << 2) + (lane >> 4);  // block row 0..31
    const int oc0 = lm << 1;                // octs 2*lm, 2*lm+1
    const float* zp = z + (size_t)(n0 + zr) * KD + (lm << 4);
    int4 p0 = pack8(zp);
    int4 p1 = pack8(zp + 8);
    const int i0 = (oc0 << 5) + (zr ^ ((oc0 & 7) << 2));
    const int i1 = ((oc0 + 1) << 5) + (zr ^ (((oc0 + 1) & 7) << 2));
    *(int4*)&smem[i0 << 4] = p0;
    *(int4*)&smem[i1 << 4] = p1;
  }
  __syncthreads();  // z8 visible to all waves

  // ---- B register pipeline: 2 named sets, 2-step lookahead ----
  const bf16x8* Bp = (const bf16x8*)e8 + ((w << 9) + (g << 7) + lm);
  f32x4 accA[8], accB[8];
  const f32x4 zzero = {0.f, 0.f, 0.f, 0.f};
#pragma unroll
  for (int nt = 0; nt < 8; ++nt) { accA[nt] = zzero; accB[nt] = zzero; }

  bf16x8 q0, q1, q2, q3, q4, q5, q6, q7;
  bf16x8 r0, r1, r2, r3, r4, r5, r6, r7;
#define LOAD8(P, T)                                                      \
  P##0 = Bp[((T) << 12)];        P##1 = Bp[((T) << 12) + 16];            \
  P##2 = Bp[((T) << 12) + 32];   P##3 = Bp[((T) << 12) + 48];            \
  P##4 = Bp[((T) << 12) + 64];   P##5 = Bp[((T) << 12) + 80];            \
  P##6 = Bp[((T) << 12) + 96];   P##7 = Bp[((T) << 12) + 112];           \
  __builtin_amdgcn_sched_barrier(0);
#define MFMA1(A0, A1, BV, NT)                                            \
  accA[NT] = __builtin_amdgcn_mfma_f32_16x16x32_bf16(A0, BV, accA[NT], 0, 0, 0); \
  accB[NT] = __builtin_amdgcn_mfma_f32_16x16x32_bf16(A1, BV, accB[NT], 0, 0, 0);
#define STEP(P, T)                                                       \
  {                                                                      \
    const int oct = ((T) << 2) + g;                                      \
    const int swz = (oct & 7) << 2;                                      \
    bf16x8 a0 = *(const bf16x8*)&smem[((oct << 5) + (lm ^ swz)) << 4];   \
    bf16x8 a1 =                                                          \
        *(const bf16x8*)&smem[((oct << 5) + ((16 + lm) ^ swz)) << 4];    \
    MFMA1(a0, a1, P##0, 0) MFMA1(a0, a1, P##1, 1) MFMA1(a0, a1, P##2, 2) \
    MFMA1(a0, a1, P##3, 3) MFMA1(a0, a1, P##4, 4) MFMA1(a0, a1, P##5, 5) \
    MFMA1(a0, a1, P##6, 6) MFMA1(a0, a1, P##7, 7)                        \
  }
  LOAD8(q, 0)
  LOAD8(r, 1)
  STEP(q, 0) LOAD8(q, 2)
  STEP(r, 1) LOAD8(r, 3)
  STEP(q, 2) LOAD8(q, 4)
  STEP(r, 3) LOAD8(r, 5)
  STEP(q, 4) LOAD8(q, 6)
  STEP(r, 5) LOAD8(r, 7)
  STEP(q, 6)
  STEP(r, 7)
#undef STEP
#undef MFMA1
#undef LOAD8

  __syncthreads();  // all waves done reading z8 -> pool overlay is safe

  // D layout: row = mt*16 + g*4 + j, col = c0 + nt*16 + lm (R7-R10 verified)
  unsigned colpack[8];
#pragma unroll
  for (int nt = 0; nt < 8; ++nt)
    colpack[nt] = 1023u - (unsigned)(c0 + (nt << 4) + lm);

  // ---- phase1: per-wave top-2 keys + wave-local exp-sum ----
  auto phase1 = [&](f32x4(&ac)[8], int mt) {
#pragma unroll
    for (int j = 0; j < 4; ++j) {
      const int r = (mt << 4) + (g << 2) + j;
      unsigned cur[8];
#pragma unroll
      for (int nt = 0; nt < 8; ++nt)
        cur[nt] = (foldf(ac[nt][j]) & 0xFFFFFC00u) | colpack[nt];
      unsigned k1 = cur[0];
#pragma unroll
      for (int nt = 1; nt < 8; ++nt) k1 = k1 > cur[nt] ? k1 : cur[nt];
#pragma unroll
      for (int d = 1; d <= 8; d <<= 1) {
        unsigned o2 = __shfl_xor(k1, d);
        k1 = k1 > o2 ? k1 : o2;
      }
      const float mw = unfoldf(k1 & 0xFFFFFC00u);
      float sum = 0.f;
#pragma unroll
      for (int nt = 0; nt < 8; ++nt) sum += __expf(ac[nt][j] - mw);
#pragma unroll
      for (int d = 1; d <= 8; d <<= 1) sum += __shfl_xor(sum, d);
#pragma unroll
      for (int nt = 0; nt < 8; ++nt)
        if (cur[nt] == k1) cur[nt] = 0u;
      unsigned k2 = cur[0];
#pragma unroll
      for (int nt = 1; nt < 8; ++nt) k2 = k2 > cur[nt] ? k2 : cur[nt];
#pragma unroll
      for (int d = 1; d <= 8; d <<= 1) {
        unsigned o2 = __shfl_xor(k2, d);
        k2 = k2 > o2 ? k2 : o2;
      }
      if (lm == 0) {
        wkey[w][0][r] = k1;
        wkey[w][1][r] = k2;
        wsum[w][r] = sum;
      }
    }
  };
  phase1(accA, 0);
  phase1(accB, 1);
  __syncthreads();

  // ---- row stats: global top-4 + lse (32 threads) ----
  if (tid < 32) {
    const int r = tid;
    unsigned best[4] = {0u, 0u, 0u, 0u};
#pragma unroll
    for (int w2 = 0; w2 < 8; ++w2)
#pragma unroll
      for (int k = 0; k < 2; ++k) {
        unsigned x = wkey[w2][k][r];
#pragma unroll
        for (int q = 0; q < 4; ++q) {
          unsigned mx = x > best[q] ? x : best[q];
          unsigned mn = x > best[q] ? best[q] : x;
          best[q] = mx;
          x = mn;
        }
      }
    const float M = unfoldf(best[0] & 0xFFFFFC00u);
    float S = 0.f;
#pragma unroll
    for (int w2 = 0; w2 < 8; ++w2)
      S += wsum[w2][r] * __expf(unfoldf(wkey[w2][0][r] & 0xFFFFFC00u) - M);
    lse_s[r] = M + __logf(S);
#pragma unroll
    for (int q = 0; q < 4; ++q) exi_s[r][q] = (int)(1023u - (best[q] & 0x3FFu));
  }
  __syncthreads();

  // ---- E4B: exact fp32 dots (z & e from global; L2/L3-resident) ----
  {
    const int row = (w << 2) + (lane >> 4);
    const int cd = (lane >> 2) & 3;
    const int seg = lane & 3;  // 64-float segment
    const int cand = exi_s[row][cd];
    const float* er = cw + (size_t)(1 + cand) * KD + (seg << 6);
    const float* zr = z + (size_t)(n0 + row) * KD + (seg << 6);
    float s = 0.f;
#pragma unroll
    for (int i2 = 0; i2 < 16; ++i2) {
      float4 a4 = *(const float4*)(zr + (i2 << 2));
      float4 b4 = *(const float4*)(er + (i2 << 2));
      s += a4.x * b4.x + a4.y * b4.y + a4.z * b4.z + a4.w * b4.w;
    }
    s += __shfl_xor(s, 1);
    s += __shfl_xor(s, 2);
    if (seg == 0) exv_s[row][cd] = s;
  }
  __syncthreads();

  // ---- final argmax (exact, first-index tiebreak) + histogram ----
  if (tid < 32) {
    const int row = tid;
    float bv = exv_s[row][0];
    int bi = exi_s[row][0];
#pragma unroll
    for (int c = 1; c < 4; ++c) {
      float v = exv_s[row][c];
      int ci = exi_s[row][c];
      if (v > bv || (v == bv && ci < bi)) { bv = v; bi = ci; }
    }
    argi[row] = bi;
    atomicAdd(&ws[WS_HIST + bi], mask[n0 + row]);  // mask=1.0 adds: exact
  }
  __syncthreads();

  // ---- E5: losses (z/mask from global; keep e rows in regs for z_q) ----
  float csum = 0.f, ssum = 0.f;
  f32x4 evs[4];
  const bool has_prev = (n0 % TT) != 0;
#pragma unroll
  for (int i = 0; i < 4; ++i) {
    const int r = (i << 3) + w;
    const int c4 = lane << 2;
    const int idx = argi[r];
    const f32x4 ev = *(const f32x4*)&cw[(size_t)(1 + idx) * KD + c4];
    evs[i] = ev;
    const f32x4 zv = *(const f32x4*)&z[(size_t)(n0 + r) * KD + c4];
    const float mk = mask[n0 + r];
    float dx = zv[0] - ev[0], dy = zv[1] - ev[1], dz2 = zv[2] - ev[2],
          dw = zv[3] - ev[3];
    csum += mk * (dx * dx + dy * dy + dz2 * dz2 + dw * dw);
    if (r > 0 || has_prev) {
      const f32x4 pv = *(const f32x4*)&z[(size_t)(n0 + r - 1) * KD + c4];
      float ax = zv[0] - pv[0], ay = zv[1] - pv[1], az = zv[2] - pv[2],
            aw = zv[3] - pv[3];
      ssum += mk * (ax * ax + ay * ay + az * az + aw * aw);
    }
  }
#pragma unroll
  for (int d = 1; d <= 32; d <<= 1) {
    csum += __shfl_xor(csum, d);
    ssum += __shfl_xor(ssum, d);
  }
  if (lane == 0) { cred[w] = csum; sred[w] = ssum; }
  __syncthreads();
  if (tid == 0) {
    float cs = 0.f, ss2 = 0.f;
#pragma unroll
    for (int i = 0; i < 8; ++i) { cs += cred[i]; ss2 += sred[i]; }
    ws[WS_CSUM + blockIdx.x] = cs;
    ws[WS_SSUM + blockIdx.x] = ss2;
    float ms = 0.f;
    for (int r2 = 0; r2 < BM; ++r2) ms += mask[n0 + r2];
    ws[WS_MSUM + blockIdx.x] = ms;
  }

  // ---- stores dead-last, nontemporal: z_q then log_probs ----
#pragma unroll
  for (int i = 0; i < 4; ++i) {
    const int r = (i << 3) + w;
    __builtin_nontemporal_store(
        evs[i], (f32x4*)&out[ZQ_OFF + (size_t)(n0 + r) * KD + (lane << 2)]);
  }
  auto phase3 = [&](f32x4(&ac)[8], int mt) {
#pragma unroll
    for (int j = 0; j < 4; ++j) {
      const int r = (mt << 4) + (g << 2) + j;
      const float lse = lse_s[r];
      size_t base = LP_OFF + (size_t)(n0 + r) * VV;
#pragma unroll
      for (int nt = 0; nt < 8; ++nt)
        __builtin_nontemporal_store(ac[nt][j] - lse,
                                    &out[base + c0 + (nt << 4) + lm]);
    }
  };
  phase3(accA, 0);
  phase3(accB, 1);
}

// ---------- fp32 fallback if ws too small ----------
__global__ __launch_bounds__(256, 2) void tok_fb(
    const float* __restrict__ z, const float* __restrict__ mask,
    const float* __restrict__ cw, float* __restrict__ out,
    float* __restrict__ ws) {
  __shared__ __align__(16) float z_s[BM][KD];
  __shared__ int argi_s[BM];
  __shared__ float cred[4], sred[4];
  const int tid = threadIdx.x;
  const int lane = tid & 63;
  const int wave = tid >> 6;
  const int n0 = blockIdx.x * BM;
  const float* e = cw + KD;
#pragma unroll
  for (int i = 0; i < 8; ++i) {
    int seg = wave * 8 + i;
    gl_lds16(&z[(size_t)(n0 + seg) * KD + lane * 4], &z_s[seg][0]);
  }
  __syncthreads();
  float acc[8][16];
#pragma unroll
  for (int r = 0; r < 8; ++r)
#pragma unroll
    for (int m = 0; m < 16; ++m) acc[r][m] = 0.f;
#pragma unroll 1
  for (int i = 0; i < 64; ++i) {
    float4 ef[16];
#pragma unroll
    for (int m = 0; m < 16; ++m)
      ef[m] = *(const float4*)&e[(size_t)((m << 6) + lane) * KD + (i << 2)];
    float4 zf[8];
#pragma unroll
    for (int rr = 0; rr < 8; ++rr)
      zf[rr] = *(const float4*)&z_s[(wave << 3) + rr][i << 2];
#pragma unroll
    for (int m = 0; m < 16; ++m)
#pragma unroll
      for (int rr = 0; rr < 8; ++rr)
        acc[rr][m] += zf[rr].x * ef[m].x + zf[rr].y * ef[m].y +
                      zf[rr].z * ef[m].z + zf[rr].w * ef[m].w;
  }
  const int rowbase = wave << 3;
#pragma unroll
  for (int rr = 0; rr < 8; ++rr) {
    float mv = acc[rr][0];
    int mc = lane;
#pragma unroll
    for (int m = 1; m < 16; ++m) {
      float v = acc[rr][m];
      int c = (m << 6) + lane;
      bool tk = v > mv;
      mc = tk ? c : mc;
      mv = tk ? v : mv;
    }
#pragma unroll
    for (int d = 32; d >= 1; d >>= 1) {
      float ov = __shfl_xor(mv, d);
      int oc = __shfl_xor(mc, d);
      bool tk = (ov > mv) || (ov == mv && oc < mc);
      mv = tk ? ov : mv;
      mc = tk ? oc : mc;
    }
    float sum = 0.f;
#pragma unroll
    for (int m = 0; m < 16; ++m) sum += __expf(acc[rr][m] - mv);
#pragma unroll
    for (int d = 32; d >= 1; d >>= 1) sum += __shfl_xor(sum, d);
    float lse = mv + __logf(sum);
    size_t base = LP_OFF + (size_t)(n0 + rowbase + rr) * VV;
#pragma unroll
    for (int m = 0; m < 16; ++m) out[base + (m << 6) + lane] = acc[rr][m] - lse;
    if (lane == 0) {
      argi_s[rowbase + rr] = mc;
      atomicAdd(&ws[WS_HIST + mc], mask[n0 + rowbase + rr]);
    }
  }
  __syncthreads();
  float csum = 0.f, ssum = 0.f;
  const bool has_prev = (n0 % TT) != 0;
#pragma unroll
  for (int i = 0; i < 8; ++i) {
    int q = i * 256 + tid;
    int r = q >> 6;
    int c4 = (q & 63) << 2;
    int idx = argi_s[r];
    const float4 ev = *(const float4*)&e[(size_t)idx * KD + c4];
    const float4 zv = *(const float4*)&z_s[r][c4];
    *(float4*)&out[ZQ_OFF + (size_t)(n0 + r) * KD + c4] = ev;
    float mk = mask[n0 + r];
    float dx = zv.x - ev.x, dy = zv.y - ev.y, dz2 = zv.z - ev.z, dw = zv.w - ev.w;
    csum += mk * (dx * dx + dy * dy + dz2 * dz2 + dw * dw);
    if (r > 0) {
      const float4 pv = *(const float4*)&z_s[r - 1][c4];
      float ax = zv.x - pv.x, ay = zv.y - pv.y, az = zv.z - pv.z, aw = zv.w - pv.w;
      ssum += mk * (ax * ax + ay * ay + az * az + aw * aw);
    } else if (has_prev) {
      const float4 pv = *(const float4*)&z[(size_t)(n0 - 1) * KD + c4];
      float ax = zv.x - pv.x, ay = zv.y - pv.y, az = zv.z - pv.z, aw = zv.w - pv.w;
      ssum += mk * (ax * ax + ay * ay + az * az + aw * aw);
    }
  }
#pragma unroll
  for (int d = 32; d >= 1; d >>= 1) {
    csum += __shfl_xor(csum, d);
    ssum += __shfl_xor(ssum, d);
  }
  if (lane == 0) { cred[wave] = csum; sred[wave] = ssum; }
  __syncthreads();
  if (tid == 0) {
    ws[WS_CSUM + blockIdx.x] = cred[0] + cred[1] + cred[2] + cred[3];
    ws[WS_SSUM + blockIdx.x] = sred[0] + sred[1] + sred[2] + sred[3];
    float ms = 0.f;
    for (int r2 = 0; r2 < BM; ++r2) ms += mask[n0 + r2];
    ws[WS_MSUM + blockIdx.x] = ms;
  }
}

__global__ __launch_bounds__(1024) void tok_final(const float* __restrict__ ws,
                                                  float* __restrict__ out) {
  const int t = threadIdx.x;
  const int lane = t & 63, w = t >> 6;
  __shared__ float red[16];
  auto blockReduce = [&](float v) -> float {
#pragma unroll
    for (int d = 32; d >= 1; d >>= 1) v += __shfl_xor(v, d);
    __syncthreads();
    if (lane == 0) red[w] = v;
    __syncthreads();
    float s = 0.f;
#pragma unroll
    for (int i = 0; i < 16; ++i) s += red[i];
    return s;
  };
  float Mtot = blockReduce(ws[WS_MSUM + t]);
  float Ctot = blockReduce(ws[WS_CSUM + t]);
  float Stot = blockReduce(ws[WS_SSUM + t]);
  float prob = ws[WS_HIST + t] / Mtot;
  float psum = blockReduce(prob);
  out[EM_OFF + t] = prob / psum;
  if (t == 0) {
    float vc = Mtot * (float)KD;
    out[0] = Stot / vc;  // smoothness_loss
    out[1] = Ctot / vc;  // commitment_loss
  }
}

extern "C" void kernel_launch(void* const* d_in, const int* in_sizes, int n_in,
                              void* d_out, int out_size, void* d_ws,
                              size_t ws_size, hipStream_t stream) {
  const float* z = (const float*)d_in[0];
  const float* mask = (const float*)d_in[1];
  const float* cw = (const float*)d_in[2];
  float* out = (float*)d_out;
  float* ws = (float*)d_ws;
  (void)hipMemsetAsync(ws, 0, 1024 * sizeof(float), stream);  // histogram
  if (ws_size >= WS_NEED) {
    unsigned short* e8 = (unsigned short*)(ws + WS_E8);
    tok_prep<<<128, 256, 0, stream>>>(cw, e8);
    tok_mfma<<<NBLK, TPB, 0, stream>>>(z, mask, cw, e8, out, ws);
  } else {
    tok_fb<<<NBLK, 256, 0, stream>>>(z, mask, cw, out, ws);
  }
  tok_final<<<1, 1024, 0, stream>>>(ws, out);
}